// Round 2
// baseline (1876.301 us; speedup 1.0000x reference)
//
#include <hip/hip_runtime.h>
#include <math.h>

__device__ __forceinline__ float silu_f(float x){ return x / (1.f + __expf(-x)); }

// ---------------- edge-index layout detect (int64 vs int32) ----------------
__global__ void k_detect(const int* __restrict__ ei, int E, int* __restrict__ flag){
  __shared__ int nz;
  if (threadIdx.x==0) nz = 0;
  __syncthreads();
  int lim = E < 4096 ? E : 4096;
  int c = 0;
  for (int e = threadIdx.x; e < lim; e += blockDim.x)
    if (ei[2*e+1] != 0) c++;
  if (c) atomicAdd(&nz, c);
  __syncthreads();
  if (threadIdx.x==0) *flag = (nz==0) ? 1 : 0;   // 1 => int64 little-endian
}

__global__ __launch_bounds__(256) void k_deg(const int* __restrict__ ei, int E,
                                             const int* __restrict__ flag, int* __restrict__ deg){
  int e = blockIdx.x*blockDim.x + threadIdx.x;
  if (e >= E) return;
  int d = (*flag) ? ei[2*(E+e)] : ei[E+e];
  atomicAdd(&deg[d], 1);
}

// ---------------- exclusive scan over N (2-level) ----------------
__global__ __launch_bounds__(256) void k_scan1(const int* __restrict__ deg, int* __restrict__ offs,
                                               int* __restrict__ bsum, int n){
  __shared__ int sh[256];
  int i = blockIdx.x*256 + threadIdx.x;
  int v = (i < n) ? deg[i] : 0;
  sh[threadIdx.x] = v;
  __syncthreads();
  for (int off=1; off<256; off<<=1){
    int t = (threadIdx.x >= off) ? sh[threadIdx.x-off] : 0;
    __syncthreads();
    sh[threadIdx.x] += t;
    __syncthreads();
  }
  if (i < n) offs[i] = sh[threadIdx.x] - v;
  if (threadIdx.x == 255) bsum[blockIdx.x] = sh[255];
}

__global__ __launch_bounds__(512) void k_scan2(int* __restrict__ bsum, int nb){
  __shared__ int sh[512];
  int v = (threadIdx.x < nb) ? bsum[threadIdx.x] : 0;
  sh[threadIdx.x] = v;
  __syncthreads();
  for (int off=1; off<512; off<<=1){
    int t = (threadIdx.x >= off) ? sh[threadIdx.x-off] : 0;
    __syncthreads();
    sh[threadIdx.x] += t;
    __syncthreads();
  }
  if (threadIdx.x < nb) bsum[threadIdx.x] = sh[threadIdx.x] - v;
}

__global__ __launch_bounds__(256) void k_scan3(int* __restrict__ offs, const int* __restrict__ bsum,
                                               int* __restrict__ cursor, int n){
  int i = blockIdx.x*256 + threadIdx.x;
  if (i >= n) return;
  int o = offs[i] + bsum[i>>8];
  offs[i] = o;
  cursor[i] = o;
}

// ---------------- per-node precompute: normalize spins, h0 ----------------
__global__ __launch_bounds__(256) void k_node_pre(const float* __restrict__ x,
                                                  const float* __restrict__ inw, const float* __restrict__ inb,
                                                  float4* __restrict__ spins4, float2* __restrict__ ntp,
                                                  float* __restrict__ h, int n){
  int half = threadIdx.x >> 7;
  int k = threadIdx.x & 127;
  int i = blockIdx.x*2 + half;
  if (i >= n) return;
  float nt0 = x[i*5+0], nt1 = x[i*5+1];
  float sx = x[i*5+2], sy = x[i*5+3], sz = x[i*5+4];
  float nrm = sqrtf(sx*sx + sy*sy + sz*sz);
  float d = fmaxf(nrm, 1e-12f);
  float mx = sx/d, my = sy/d, mz = sz/d;
  float rn = sqrtf(mx*mx + my*my + mz*mz);
  float v = nt0*inw[k] + nt1*inw[128+k] + rn*inw[256+k] + inb[k];
  h[i*128 + k] = silu_f(v);
  if (k == 0){
    spins4[i] = make_float4(mx, my, mz, rn);
    ntp[i]    = make_float2(nt0, nt1);
  }
}

// ---------------- scatter edges into dst-sorted order ----------------
__global__ __launch_bounds__(256) void k_scatter(const int* __restrict__ ei, int E,
                                                 const int* __restrict__ flag,
                                                 const float* __restrict__ eattr, int* __restrict__ cursor,
                                                 int* __restrict__ srcS, float4* __restrict__ attrS){
  int e = blockIdx.x*blockDim.x + threadIdx.x;
  if (e >= E) return;
  int i64 = *flag;
  int s = i64 ? ei[2*e]       : ei[e];
  int d = i64 ? ei[2*(E+e)]   : ei[E+e];
  int pos = atomicAdd(&cursor[d], 1);
  srcS[pos] = s;
  attrS[pos] = *(const float4*)(eattr + (size_t)e*4);
}

// ---------------- edge MLP hidden sums for ONE layer (wave per node) ----------------
__global__ __launch_bounds__(256) void k_edge(
    const int* __restrict__ srcS, const float4* __restrict__ attrS,
    const float4* __restrict__ spins4, const float2* __restrict__ ntp,
    const int* __restrict__ offs, const int* __restrict__ deg,
    const float* __restrict__ ew1l, const float* __restrict__ eb1l,
    float* __restrict__ A, int n){
  int wv = threadIdx.x >> 6, lane = threadIdx.x & 63;
  int i = blockIdx.x*4 + wv;
  if (i >= n) return;
  float w[10][2], b0, b1;
  #pragma unroll
  for (int j=0;j<10;j++){
    w[j][0] = ew1l[j*128 + lane];
    w[j][1] = ew1l[j*128 + 64 + lane];
  }
  b0 = eb1l[lane];
  b1 = eb1l[64 + lane];
  float4 nd = spins4[i];
  float2 nti = ntp[i];
  float a0 = 0.f, a1 = 0.f;
  int p0 = offs[i], e = deg[i];
  for (int q=0;q<e;q++){
    int s = srcS[p0+q];
    float4 ms = spins4[s];
    float2 nts = ntp[s];
    float4 ea = attrS[p0+q];
    float sc[10];
    sc[0] = nd.w;
    sc[1] = ms.w;
    sc[2] = nd.x*ms.x + nd.y*ms.y + nd.z*ms.z;
    sc[3] = nd.x*ea.x + nd.y*ea.y + nd.z*ea.z;
    sc[4] = ms.x*ea.x + ms.y*ea.y + ms.z*ea.z;
    sc[5] = ea.w;
    sc[6] = nti.x; sc[7] = nti.y;
    sc[8] = nts.x; sc[9] = nts.y;
    float t0 = b0, t1 = b1;
    #pragma unroll
    for (int j=0;j<10;j++){ t0 += sc[j]*w[j][0]; t1 += sc[j]*w[j][1]; }
    a0 += silu_f(t0);
    a1 += silu_f(t1);
  }
  A[(size_t)i*128 + lane]      = a0;
  A[(size_t)i*128 + 64 + lane] = a1;
}

// ---------------- fused per-layer node update ----------------
// aggr = A@ew2 + deg*eb2 ; u = silu([h,aggr]@nw1 + nb1) ; h += u@nw2 + nb2
__global__ __launch_bounds__(256) void k_layer(
    const float* __restrict__ A, float* __restrict__ h,
    const float* __restrict__ ew2, const float* __restrict__ eb2,
    const float* __restrict__ nw1, const float* __restrict__ nb1,
    const float* __restrict__ nw2, const float* __restrict__ nb2,
    const int* __restrict__ deg, int n){
  __shared__ float sS[32][128];   // raw A tile, later reused for u
  __shared__ float sH[32][128];   // h tile
  __shared__ float sU[32][128];   // aggr tile
  int row0 = blockIdx.x * 32;
  int tid = threadIdx.x;
  int tx = tid & 31, ty = tid >> 5;
  int c0 = tx << 2;
  // load A tile and h tile
  #pragma unroll
  for (int q=0;q<4;q++){
    int f4 = tid + q*256;
    int r = f4 >> 5;
    int j = (f4 & 31) << 2;
    int row = row0 + r;
    float4 va = make_float4(0.f,0.f,0.f,0.f);
    float4 vh = make_float4(0.f,0.f,0.f,0.f);
    if (row < n){
      va = *(const float4*)(A + (size_t)row*128 + j);
      vh = *(const float4*)(h + (size_t)row*128 + j);
    }
    *(float4*)&sS[r][j] = va;
    *(float4*)&sH[r][j] = vh;
  }
  __syncthreads();

  float acc[4][4];
  // ---- GEMM-A: aggr = sS @ ew2 + deg*eb2 -> sU ----
  #pragma unroll
  for (int a=0;a<4;a++){ acc[a][0]=0.f; acc[a][1]=0.f; acc[a][2]=0.f; acc[a][3]=0.f; }
  #pragma unroll 8
  for (int j=0;j<128;j+=4){
    float4 W0 = *(const float4*)(ew2 + (j+0)*128 + c0);
    float4 W1 = *(const float4*)(ew2 + (j+1)*128 + c0);
    float4 W2 = *(const float4*)(ew2 + (j+2)*128 + c0);
    float4 W3 = *(const float4*)(ew2 + (j+3)*128 + c0);
    #pragma unroll
    for (int rr=0;rr<4;rr++){
      float4 a = *(const float4*)&sS[(ty<<2)+rr][j];
      acc[rr][0] += a.x*W0.x + a.y*W1.x + a.z*W2.x + a.w*W3.x;
      acc[rr][1] += a.x*W0.y + a.y*W1.y + a.z*W2.y + a.w*W3.y;
      acc[rr][2] += a.x*W0.z + a.y*W1.z + a.z*W2.z + a.w*W3.z;
      acc[rr][3] += a.x*W0.w + a.y*W1.w + a.z*W2.w + a.w*W3.w;
    }
  }
  {
    float4 bv = *(const float4*)(eb2 + c0);
    #pragma unroll
    for (int rr=0;rr<4;rr++){
      int r = (ty<<2)+rr;
      int row = row0 + r;
      float dd = (row < n) ? (float)deg[row] : 0.f;
      sU[r][c0+0] = acc[rr][0] + dd*bv.x;
      sU[r][c0+1] = acc[rr][1] + dd*bv.y;
      sU[r][c0+2] = acc[rr][2] + dd*bv.z;
      sU[r][c0+3] = acc[rr][3] + dd*bv.w;
    }
  }
  __syncthreads();

  // ---- GEMM-B: u = silu([sH | sU] @ nw1 + nb1) -> sS ----
  #pragma unroll
  for (int a=0;a<4;a++){ acc[a][0]=0.f; acc[a][1]=0.f; acc[a][2]=0.f; acc[a][3]=0.f; }
  #pragma unroll
  for (int pass=0; pass<2; ++pass){
    const float* Wp = nw1 + (size_t)pass*128*128;
    #pragma unroll 8
    for (int j=0;j<128;j+=4){
      float4 W0 = *(const float4*)(Wp + (j+0)*128 + c0);
      float4 W1 = *(const float4*)(Wp + (j+1)*128 + c0);
      float4 W2 = *(const float4*)(Wp + (j+2)*128 + c0);
      float4 W3 = *(const float4*)(Wp + (j+3)*128 + c0);
      #pragma unroll
      for (int rr=0;rr<4;rr++){
        float4 a = pass==0 ? *(const float4*)&sH[(ty<<2)+rr][j]
                           : *(const float4*)&sU[(ty<<2)+rr][j];
        acc[rr][0] += a.x*W0.x + a.y*W1.x + a.z*W2.x + a.w*W3.x;
        acc[rr][1] += a.x*W0.y + a.y*W1.y + a.z*W2.y + a.w*W3.y;
        acc[rr][2] += a.x*W0.z + a.y*W1.z + a.z*W2.z + a.w*W3.z;
        acc[rr][3] += a.x*W0.w + a.y*W1.w + a.z*W2.w + a.w*W3.w;
      }
    }
  }
  {
    float4 bv = *(const float4*)(nb1 + c0);
    #pragma unroll
    for (int rr=0;rr<4;rr++){
      int r = (ty<<2)+rr;
      sS[r][c0+0] = silu_f(acc[rr][0] + bv.x);
      sS[r][c0+1] = silu_f(acc[rr][1] + bv.y);
      sS[r][c0+2] = silu_f(acc[rr][2] + bv.z);
      sS[r][c0+3] = silu_f(acc[rr][3] + bv.w);
    }
  }
  __syncthreads();

  // ---- GEMM-C: h = sH + sS(u) @ nw2 + nb2 -> global ----
  #pragma unroll
  for (int a=0;a<4;a++){ acc[a][0]=0.f; acc[a][1]=0.f; acc[a][2]=0.f; acc[a][3]=0.f; }
  #pragma unroll 8
  for (int j=0;j<128;j+=4){
    float4 W0 = *(const float4*)(nw2 + (j+0)*128 + c0);
    float4 W1 = *(const float4*)(nw2 + (j+1)*128 + c0);
    float4 W2 = *(const float4*)(nw2 + (j+2)*128 + c0);
    float4 W3 = *(const float4*)(nw2 + (j+3)*128 + c0);
    #pragma unroll
    for (int rr=0;rr<4;rr++){
      float4 a = *(const float4*)&sS[(ty<<2)+rr][j];
      acc[rr][0] += a.x*W0.x + a.y*W1.x + a.z*W2.x + a.w*W3.x;
      acc[rr][1] += a.x*W0.y + a.y*W1.y + a.z*W2.y + a.w*W3.y;
      acc[rr][2] += a.x*W0.z + a.y*W1.z + a.z*W2.z + a.w*W3.z;
      acc[rr][3] += a.x*W0.w + a.y*W1.w + a.z*W2.w + a.w*W3.w;
    }
  }
  {
    float4 bv = *(const float4*)(nb2 + c0);
    #pragma unroll
    for (int rr=0;rr<4;rr++){
      int r = (ty<<2)+rr;
      int row = row0 + r;
      if (row >= n) continue;
      float4 o;
      o.x = sH[r][c0+0] + acc[rr][0] + bv.x;
      o.y = sH[r][c0+1] + acc[rr][1] + bv.y;
      o.z = sH[r][c0+2] + acc[rr][2] + bv.z;
      o.w = sH[r][c0+3] + acc[rr][3] + bv.w;
      *(float4*)(h + (size_t)row*128 + c0) = o;
    }
  }
}

// ---------------- fused output head: wout = silu(h@ow1+ob1)·ow2 + ob2 ----------------
__global__ __launch_bounds__(256) void k_out(const float* __restrict__ h,
                                             const float* __restrict__ ow1, const float* __restrict__ ob1,
                                             const float* __restrict__ ow2, const float* __restrict__ ob2,
                                             float* __restrict__ wout, int n){
  __shared__ float sH[32][128];
  int row0 = blockIdx.x * 32;
  int tid = threadIdx.x;
  int tx = tid & 31, ty = tid >> 5;
  int c0 = tx << 2;
  #pragma unroll
  for (int q=0;q<4;q++){
    int f4 = tid + q*256;
    int r = f4 >> 5;
    int j = (f4 & 31) << 2;
    int row = row0 + r;
    float4 vh = make_float4(0.f,0.f,0.f,0.f);
    if (row < n) vh = *(const float4*)(h + (size_t)row*128 + j);
    *(float4*)&sH[r][j] = vh;
  }
  __syncthreads();
  float acc[4][4];
  #pragma unroll
  for (int a=0;a<4;a++){ acc[a][0]=0.f; acc[a][1]=0.f; acc[a][2]=0.f; acc[a][3]=0.f; }
  #pragma unroll 8
  for (int j=0;j<128;j+=4){
    float4 W0 = *(const float4*)(ow1 + (j+0)*128 + c0);
    float4 W1 = *(const float4*)(ow1 + (j+1)*128 + c0);
    float4 W2 = *(const float4*)(ow1 + (j+2)*128 + c0);
    float4 W3 = *(const float4*)(ow1 + (j+3)*128 + c0);
    #pragma unroll
    for (int rr=0;rr<4;rr++){
      float4 a = *(const float4*)&sH[(ty<<2)+rr][j];
      acc[rr][0] += a.x*W0.x + a.y*W1.x + a.z*W2.x + a.w*W3.x;
      acc[rr][1] += a.x*W0.y + a.y*W1.y + a.z*W2.y + a.w*W3.y;
      acc[rr][2] += a.x*W0.z + a.y*W1.z + a.z*W2.z + a.w*W3.z;
      acc[rr][3] += a.x*W0.w + a.y*W1.w + a.z*W2.w + a.w*W3.w;
    }
  }
  float4 bv = *(const float4*)(ob1 + c0);
  float4 w2 = *(const float4*)(ow2 + c0);
  float p[4];
  #pragma unroll
  for (int rr=0;rr<4;rr++){
    float u0 = silu_f(acc[rr][0] + bv.x);
    float u1 = silu_f(acc[rr][1] + bv.y);
    float u2 = silu_f(acc[rr][2] + bv.z);
    float u3 = silu_f(acc[rr][3] + bv.w);
    p[rr] = u0*w2.x + u1*w2.y + u2*w2.z + u3*w2.w;
  }
  // reduce across tx (lanes within a 32-half of the wave)
  #pragma unroll
  for (int m=1;m<32;m<<=1){
    #pragma unroll
    for (int rr=0;rr<4;rr++) p[rr] += __shfl_xor(p[rr], m, 64);
  }
  if (tx == 0){
    float b = ob2[0];
    #pragma unroll
    for (int rr=0;rr<4;rr++){
      int row = row0 + (ty<<2) + rr;
      if (row < n) wout[row] = p[rr] + b;
    }
  }
}

// ---------------- b_field: gather-sum weight[src]*spins[src] per node ----------------
__global__ __launch_bounds__(256) void k_bfield(const int* __restrict__ srcS, const float4* __restrict__ spins4,
                                                const float* __restrict__ wout, const int* __restrict__ offs,
                                                const int* __restrict__ deg, float* __restrict__ out, int n){
  int wv = threadIdx.x >> 6, lane = threadIdx.x & 63;
  int i = blockIdx.x*4 + wv;
  if (i >= n) return;
  int p0 = offs[i], e = deg[i];
  float ax=0.f, ay=0.f, az=0.f;
  for (int q=lane; q<e; q+=64){
    int s = srcS[p0+q];
    float wg = wout[s];
    float4 sp = spins4[s];
    ax += wg*sp.x; ay += wg*sp.y; az += wg*sp.z;
  }
  #pragma unroll
  for (int m=32;m>0;m>>=1){
    ax += __shfl_xor(ax, m, 64);
    ay += __shfl_xor(ay, m, 64);
    az += __shfl_xor(az, m, 64);
  }
  if (lane == 0){
    out[(size_t)i*3+0] = ax;
    out[(size_t)i*3+1] = ay;
    out[(size_t)i*3+2] = az;
  }
}

extern "C" void kernel_launch(void* const* d_in, const int* in_sizes, int n_in,
                              void* d_out, int out_size, void* d_ws, size_t ws_size,
                              hipStream_t stream){
  const float* x      = (const float*)d_in[0];
  const int*   ei     = (const int*)  d_in[1];
  const float* eattr  = (const float*)d_in[2];
  const float* in_w   = (const float*)d_in[3];
  const float* in_b   = (const float*)d_in[4];
  const float* ew1    = (const float*)d_in[5];
  const float* eb1    = (const float*)d_in[6];
  const float* ew2    = (const float*)d_in[7];
  const float* eb2    = (const float*)d_in[8];
  const float* nw1    = (const float*)d_in[9];
  const float* nb1    = (const float*)d_in[10];
  const float* nw2    = (const float*)d_in[11];
  const float* nb2    = (const float*)d_in[12];
  const float* ow1    = (const float*)d_in[13];
  const float* ob1    = (const float*)d_in[14];
  const float* ow2    = (const float*)d_in[15];
  const float* ob2    = (const float*)d_in[16];
  float* out = (float*)d_out;

  const int N = in_sizes[0] / 5;
  const int E = in_sizes[1] / 2;

  char* w = (char*)d_ws;
  size_t off = 0;
  auto alloc = [&](size_t bytes)->size_t{
    size_t o = off; off = (off + bytes + 255) & ~(size_t)255; return o;
  };
  size_t o_flag   = alloc(4);
  size_t o_deg    = alloc((size_t)N*4);
  size_t o_offs   = alloc((size_t)N*4);
  size_t o_cursor = alloc((size_t)N*4);
  size_t o_bsum   = alloc(512*4);
  size_t o_spins4 = alloc((size_t)N*16);
  size_t o_ntp    = alloc((size_t)N*8);
  size_t o_wout   = alloc((size_t)N*4);
  size_t o_srcS   = alloc((size_t)E*4);
  size_t o_attrS  = alloc((size_t)E*16);
  size_t o_h      = alloc((size_t)N*128*4);
  size_t o_A      = alloc((size_t)N*128*4);
  if (off > ws_size) return;

  int*    flag   = (int*)   (w + o_flag);
  int*    deg    = (int*)   (w + o_deg);
  int*    offs   = (int*)   (w + o_offs);
  int*    cursor = (int*)   (w + o_cursor);
  int*    bsum   = (int*)   (w + o_bsum);
  float4* spins4 = (float4*)(w + o_spins4);
  float2* ntp    = (float2*)(w + o_ntp);
  float*  wout   = (float*) (w + o_wout);
  int*    srcS   = (int*)   (w + o_srcS);
  float4* attrS  = (float4*)(w + o_attrS);
  float*  h      = (float*) (w + o_h);
  float*  A      = (float*) (w + o_A);

  hipMemsetAsync(deg, 0, (size_t)N*4, stream);

  const int nb = (N + 255) / 256;

  k_detect<<<1, 256, 0, stream>>>(ei, E, flag);
  k_deg<<<(E+255)/256, 256, 0, stream>>>(ei, E, flag, deg);
  k_scan1<<<nb, 256, 0, stream>>>(deg, offs, bsum, N);
  k_scan2<<<1, 512, 0, stream>>>(bsum, nb);
  k_scan3<<<nb, 256, 0, stream>>>(offs, bsum, cursor, N);
  k_node_pre<<<(N+1)/2, 256, 0, stream>>>(x, in_w, in_b, spins4, ntp, h, N);
  k_scatter<<<(E+255)/256, 256, 0, stream>>>(ei, E, flag, eattr, cursor, srcS, attrS);

  const int gb = (N + 31) / 32;
  for (int l=0; l<3; ++l){
    k_edge<<<(N+3)/4, 256, 0, stream>>>(srcS, attrS, spins4, ntp, offs, deg,
                                        ew1 + (size_t)l*10*128, eb1 + (size_t)l*128, A, N);
    k_layer<<<gb, 256, 0, stream>>>(A, h,
                                    ew2 + (size_t)l*128*128, eb2 + (size_t)l*128,
                                    nw1 + (size_t)l*256*128, nb1 + (size_t)l*128,
                                    nw2 + (size_t)l*128*128, nb2 + (size_t)l*128,
                                    deg, N);
  }

  k_out<<<gb, 256, 0, stream>>>(h, ow1, ob1, ow2, ob2, wout, N);
  k_bfield<<<(N+3)/4, 256, 0, stream>>>(srcS, spins4, wout, offs, deg, out, N);
}

// Round 4
// 1191.375 us; speedup vs baseline: 1.5749x; 1.5749x over previous
//
#include <hip/hip_runtime.h>
#include <hip/hip_bf16.h>
#include <math.h>

typedef __attribute__((ext_vector_type(8))) short bf16x8;
typedef __attribute__((ext_vector_type(4))) float f32x4;

__device__ __forceinline__ float silu_f(float x){ return x / (1.f + __expf(-x)); }

// fp32 -> bf16 (round-to-nearest-even, finite inputs)
__device__ __forceinline__ short f2bs(float x){
  unsigned u = __builtin_bit_cast(unsigned, x);
  unsigned r = (u + 0x7fffu + ((u >> 16) & 1u)) >> 16;
  return (short)r;
}

// ---------------- edge-index layout detect (int64 vs int32) ----------------
__global__ void k_detect(const int* __restrict__ ei, int E, int* __restrict__ flag){
  __shared__ int nz;
  if (threadIdx.x==0) nz = 0;
  __syncthreads();
  int lim = E < 4096 ? E : 4096;
  int c = 0;
  for (int e = threadIdx.x; e < lim; e += blockDim.x)
    if (ei[2*e+1] != 0) c++;
  if (c) atomicAdd(&nz, c);
  __syncthreads();
  if (threadIdx.x==0) *flag = (nz==0) ? 1 : 0;   // 1 => int64 little-endian
}

__global__ __launch_bounds__(256) void k_deg(const int* __restrict__ ei, int E,
                                             const int* __restrict__ flag, int* __restrict__ deg){
  int e = blockIdx.x*blockDim.x + threadIdx.x;
  if (e >= E) return;
  int d = (*flag) ? ei[2*(E+e)] : ei[E+e];
  atomicAdd(&deg[d], 1);
}

// ---------------- exclusive scan over N (2-level) ----------------
__global__ __launch_bounds__(256) void k_scan1(const int* __restrict__ deg, int* __restrict__ offs,
                                               int* __restrict__ bsum, int n){
  __shared__ int sh[256];
  int i = blockIdx.x*256 + threadIdx.x;
  int v = (i < n) ? deg[i] : 0;
  sh[threadIdx.x] = v;
  __syncthreads();
  for (int off=1; off<256; off<<=1){
    int t = (threadIdx.x >= off) ? sh[threadIdx.x-off] : 0;
    __syncthreads();
    sh[threadIdx.x] += t;
    __syncthreads();
  }
  if (i < n) offs[i] = sh[threadIdx.x] - v;
  if (threadIdx.x == 255) bsum[blockIdx.x] = sh[255];
}

__global__ __launch_bounds__(512) void k_scan2(int* __restrict__ bsum, int nb){
  __shared__ int sh[512];
  int v = (threadIdx.x < nb) ? bsum[threadIdx.x] : 0;
  sh[threadIdx.x] = v;
  __syncthreads();
  for (int off=1; off<512; off<<=1){
    int t = (threadIdx.x >= off) ? sh[threadIdx.x-off] : 0;
    __syncthreads();
    sh[threadIdx.x] += t;
    __syncthreads();
  }
  if (threadIdx.x < nb) bsum[threadIdx.x] = sh[threadIdx.x] - v;
}

__global__ __launch_bounds__(256) void k_scan3(int* __restrict__ offs, const int* __restrict__ bsum,
                                               int* __restrict__ cursor, int n){
  int i = blockIdx.x*256 + threadIdx.x;
  if (i >= n) return;
  int o = offs[i] + bsum[i>>8];
  offs[i] = o;
  cursor[i] = o;
}

// ---------------- per-node precompute: normalize spins, h0 ----------------
__global__ __launch_bounds__(256) void k_node_pre(const float* __restrict__ x,
                                                  const float* __restrict__ inw, const float* __restrict__ inb,
                                                  float4* __restrict__ spins4, float2* __restrict__ ntp,
                                                  float* __restrict__ h, int n){
  int half = threadIdx.x >> 7;
  int k = threadIdx.x & 127;
  int i = blockIdx.x*2 + half;
  if (i >= n) return;
  float nt0 = x[i*5+0], nt1 = x[i*5+1];
  float sx = x[i*5+2], sy = x[i*5+3], sz = x[i*5+4];
  float nrm = sqrtf(sx*sx + sy*sy + sz*sz);
  float d = fmaxf(nrm, 1e-12f);
  float mx = sx/d, my = sy/d, mz = sz/d;
  float rn = sqrtf(mx*mx + my*my + mz*mz);
  float v = nt0*inw[k] + nt1*inw[128+k] + rn*inw[256+k] + inb[k];
  h[i*128 + k] = silu_f(v);
  if (k == 0){
    spins4[i] = make_float4(mx, my, mz, rn);
    ntp[i]    = make_float2(nt0, nt1);
  }
}

// ---------------- scatter edges into dst-sorted order ----------------
__global__ __launch_bounds__(256) void k_scatter(const int* __restrict__ ei, int E,
                                                 const int* __restrict__ flag,
                                                 const float* __restrict__ eattr, int* __restrict__ cursor,
                                                 int* __restrict__ srcS, float4* __restrict__ attrS){
  int e = blockIdx.x*blockDim.x + threadIdx.x;
  if (e >= E) return;
  int i64 = *flag;
  int s = i64 ? ei[2*e]       : ei[e];
  int d = i64 ? ei[2*(E+e)]   : ei[E+e];
  int pos = atomicAdd(&cursor[d], 1);
  srcS[pos] = s;
  attrS[pos] = *(const float4*)(eattr + (size_t)e*4);
}

// ---------------- pack weights to MFMA B-fragment-major bf16 ----------------
// B-frag (16x16x32): lane L holds B[k=(L>>4)*8+e][n=L&15]; tile index = c*8+t
__global__ __launch_bounds__(64) void k_pack(const float* __restrict__ ew2, const float* __restrict__ nw1,
                                             const float* __restrict__ nw2, const float* __restrict__ ow1,
                                             short* __restrict__ p_ew2, short* __restrict__ p_nw1,
                                             short* __restrict__ p_nw2, short* __restrict__ p_ow1){
  int b = blockIdx.x;
  const float* src; short* dst; int tile;
  if (b < 96){        int l = b>>5;              tile = b & 31; src = ew2 + (size_t)l*16384; dst = p_ew2 + (size_t)l*16384; }
  else if (b < 288){  int l = (b-96)>>6;         tile = (b-96) & 63; src = nw1 + (size_t)l*32768; dst = p_nw1 + (size_t)l*32768; }
  else if (b < 384){  int l = (b-288)>>5;        tile = (b-288) & 31; src = nw2 + (size_t)l*16384; dst = p_nw2 + (size_t)l*16384; }
  else {                                          tile = b - 384; src = ow1; dst = p_ow1; }
  int c = tile >> 3, t = tile & 7;
  int L = threadIdx.x;
  int kb  = c*32 + ((L>>4)<<3);
  int col = t*16 + (L&15);
  __align__(16) short tmp[8];
  #pragma unroll
  for (int e=0;e<8;e++) tmp[e] = f2bs(src[(size_t)(kb+e)*128 + col]);
  *(bf16x8*)(dst + ((size_t)tile*64 + L)*8) = *(bf16x8*)tmp;
}

// ---------------- edge MLP hidden sums for ONE layer (wave per node), bf16 out ----------------
__global__ __launch_bounds__(256) void k_edge(
    const int* __restrict__ srcS, const float4* __restrict__ attrS,
    const float4* __restrict__ spins4, const float2* __restrict__ ntp,
    const int* __restrict__ offs, const int* __restrict__ deg,
    const float* __restrict__ ew1l, const float* __restrict__ eb1l,
    ushort* __restrict__ A, int n){
  int wv = threadIdx.x >> 6, lane = threadIdx.x & 63;
  int i = blockIdx.x*4 + wv;
  if (i >= n) return;
  float w[10][2], b0, b1;
  #pragma unroll
  for (int j=0;j<10;j++){
    w[j][0] = ew1l[j*128 + lane];
    w[j][1] = ew1l[j*128 + 64 + lane];
  }
  b0 = eb1l[lane];
  b1 = eb1l[64 + lane];
  float4 nd = spins4[i];
  float2 nti = ntp[i];
  float a0 = 0.f, a1 = 0.f;
  int p0 = offs[i], e = deg[i];
  for (int q=0;q<e;q++){
    int s = srcS[p0+q];
    float4 ms = spins4[s];
    float2 nts = ntp[s];
    float4 ea = attrS[p0+q];
    float sc[10];
    sc[0] = nd.w;
    sc[1] = ms.w;
    sc[2] = nd.x*ms.x + nd.y*ms.y + nd.z*ms.z;
    sc[3] = nd.x*ea.x + nd.y*ea.y + nd.z*ea.z;
    sc[4] = ms.x*ea.x + ms.y*ea.y + ms.z*ea.z;
    sc[5] = ea.w;
    sc[6] = nti.x; sc[7] = nti.y;
    sc[8] = nts.x; sc[9] = nts.y;
    float t0 = b0, t1 = b1;
    #pragma unroll
    for (int j=0;j<10;j++){ t0 += sc[j]*w[j][0]; t1 += sc[j]*w[j][1]; }
    a0 += silu_f(t0);
    a1 += silu_f(t1);
  }
  A[(size_t)i*128 + lane]      = (ushort)f2bs(a0);
  A[(size_t)i*128 + 64 + lane] = (ushort)f2bs(a1);
}

// ---------------- MFMA wave GEMM: 16 rows x 128 cols, K = kchunks*32 ----------------
// sIn: bf16 LDS stripe (stride 136); pw: fragment-major packed weights
__device__ __forceinline__ void wave_gemm(const short* __restrict__ sIn, const short* __restrict__ pw,
                                          int lane, int kchunks, f32x4 acc[8]){
  for (int c=0;c<kchunks;c++){
    bf16x8 af = *(const bf16x8*)(sIn + (lane&15)*136 + c*32 + ((lane>>4)<<3));
    const short* pB = pw + (size_t)c*4096 + (size_t)lane*8;
    #pragma unroll
    for (int t=0;t<8;t++){
      bf16x8 bf = *(const bf16x8*)(pB + t*512);
      acc[t] = __builtin_amdgcn_mfma_f32_16x16x32_bf16(af, bf, acc[t], 0, 0, 0);
    }
  }
}

// ---------------- fused per-layer node update (MFMA) ----------------
// aggr = A@ew2 + deg*eb2 ; u = silu([h,aggr]@nw1 + nb1) ; h += u@nw2 + nb2
__global__ __launch_bounds__(256) void k_layer(
    const ushort* __restrict__ A, float* __restrict__ h,
    const short* __restrict__ p_ew2, const float* __restrict__ eb2,
    const short* __restrict__ p_nw1, const float* __restrict__ nb1,
    const short* __restrict__ p_nw2, const float* __restrict__ nb2,
    const int* __restrict__ deg, int n){
  __shared__ __align__(16) short sA[64*136];
  __shared__ __align__(16) short sH[64*136];
  __shared__ __align__(16) short sG[64*136];
  int tid = threadIdx.x;
  int lane = tid & 63, wave = tid >> 6;
  int row0 = blockIdx.x*64;

  // stage A (bf16 copy) and h (fp32 -> bf16)
  #pragma unroll
  for (int q=0;q<8;q++){
    int id = tid + q*256;            // 2048 quads of 4 elems
    int r = id >> 5;
    int cq = (id & 31) << 2;
    int row = row0 + r;
    ushort4 va = make_ushort4(0,0,0,0);
    float4 vh = make_float4(0.f,0.f,0.f,0.f);
    if (row < n){
      va = *(const ushort4*)(A + (size_t)row*128 + cq);
      vh = *(const float4*)(h + (size_t)row*128 + cq);
    }
    *(ushort4*)&sA[r*136 + cq] = va;
    short4 hs; hs.x = f2bs(vh.x); hs.y = f2bs(vh.y); hs.z = f2bs(vh.z); hs.w = f2bs(vh.w);
    *(short4*)&sH[r*136 + cq] = hs;
  }
  __syncthreads();

  const short* sInA = sA + wave*16*136;
  const short* sInH = sH + wave*16*136;
  const short* sInG = sG + wave*16*136;
  int rbase = wave*16 + ((lane>>4)<<2);   // first of this lane's 4 C-rows (block-local)

  f32x4 acc[8];
  const f32x4 zf = {0.f,0.f,0.f,0.f};

  // ---- GEMM-A: aggr = A @ ew2 + deg*eb2 -> sG (bf16) ----
  #pragma unroll
  for (int t=0;t<8;t++) acc[t] = zf;
  wave_gemm(sInA, p_ew2, lane, 4, acc);
  {
    float dd[4];
    #pragma unroll
    for (int r=0;r<4;r++){
      int row = row0 + rbase + r;
      dd[r] = (row < n) ? (float)deg[row] : 0.f;
    }
    #pragma unroll
    for (int t=0;t<8;t++){
      int col = t*16 + (lane&15);
      float bv = eb2[col];
      #pragma unroll
      for (int r=0;r<4;r++)
        sG[(rbase+r)*136 + col] = f2bs(acc[t][r] + dd[r]*bv);
    }
  }
  __syncthreads();

  // ---- GEMM-B: u = silu([h|aggr] @ nw1 + nb1) -> sA (bf16) ----
  #pragma unroll
  for (int t=0;t<8;t++) acc[t] = zf;
  wave_gemm(sInH, p_nw1,         lane, 4, acc);
  wave_gemm(sInG, p_nw1 + 16384, lane, 4, acc);
  __syncthreads();   // everyone done reading sA (GEMM-A) before overwrite
  {
    #pragma unroll
    for (int t=0;t<8;t++){
      int col = t*16 + (lane&15);
      float bv = nb1[col];
      #pragma unroll
      for (int r=0;r<4;r++)
        sA[(rbase+r)*136 + col] = f2bs(silu_f(acc[t][r] + bv));
    }
  }
  __syncthreads();

  // ---- GEMM-C: h += u @ nw2 + nb2 ----
  #pragma unroll
  for (int t=0;t<8;t++) acc[t] = zf;
  wave_gemm(sInA, p_nw2, lane, 4, acc);
  {
    #pragma unroll
    for (int t=0;t<8;t++){
      int col = t*16 + (lane&15);
      float bv = nb2[col];
      #pragma unroll
      for (int r=0;r<4;r++){
        int row = row0 + rbase + r;
        if (row < n){
          size_t idx = (size_t)row*128 + col;
          h[idx] = h[idx] + acc[t][r] + bv;
        }
      }
    }
  }
}

// ---------------- fused output head (MFMA): wout = silu(h@ow1+ob1)·ow2 + ob2 ----------------
__global__ __launch_bounds__(256) void k_out(const float* __restrict__ h,
                                             const short* __restrict__ p_ow1, const float* __restrict__ ob1,
                                             const float* __restrict__ ow2, const float* __restrict__ ob2,
                                             float* __restrict__ wout, int n){
  __shared__ __align__(16) short sH[64*136];
  int tid = threadIdx.x;
  int lane = tid & 63, wave = tid >> 6;
  int row0 = blockIdx.x*64;
  #pragma unroll
  for (int q=0;q<8;q++){
    int id = tid + q*256;
    int r = id >> 5;
    int cq = (id & 31) << 2;
    int row = row0 + r;
    float4 vh = make_float4(0.f,0.f,0.f,0.f);
    if (row < n) vh = *(const float4*)(h + (size_t)row*128 + cq);
    short4 hs; hs.x = f2bs(vh.x); hs.y = f2bs(vh.y); hs.z = f2bs(vh.z); hs.w = f2bs(vh.w);
    *(short4*)&sH[r*136 + cq] = hs;
  }
  __syncthreads();

  f32x4 acc[8];
  const f32x4 zf = {0.f,0.f,0.f,0.f};
  #pragma unroll
  for (int t=0;t<8;t++) acc[t] = zf;
  wave_gemm(sH + wave*16*136, p_ow1, lane, 4, acc);

  float p[4] = {0.f,0.f,0.f,0.f};
  #pragma unroll
  for (int t=0;t<8;t++){
    int col = t*16 + (lane&15);
    float b1 = ob1[col], w2 = ow2[col];
    #pragma unroll
    for (int r=0;r<4;r++) p[r] += silu_f(acc[t][r] + b1)*w2;
  }
  #pragma unroll
  for (int m=1;m<16;m<<=1){
    #pragma unroll
    for (int r=0;r<4;r++) p[r] += __shfl_xor(p[r], m, 64);
  }
  if ((lane & 15) == 0){
    float b = ob2[0];
    #pragma unroll
    for (int r=0;r<4;r++){
      int row = row0 + wave*16 + ((lane>>4)<<2) + r;
      if (row < n) wout[row] = p[r] + b;
    }
  }
}

// ---------------- b_field: gather-sum weight[src]*spins[src] per node ----------------
__global__ __launch_bounds__(256) void k_bfield(const int* __restrict__ srcS, const float4* __restrict__ spins4,
                                                const float* __restrict__ wout, const int* __restrict__ offs,
                                                const int* __restrict__ deg, float* __restrict__ out, int n){
  int wv = threadIdx.x >> 6, lane = threadIdx.x & 63;
  int i = blockIdx.x*4 + wv;
  if (i >= n) return;
  int p0 = offs[i], e = deg[i];
  float ax=0.f, ay=0.f, az=0.f;
  for (int q=lane; q<e; q+=64){
    int s = srcS[p0+q];
    float wg = wout[s];
    float4 sp = spins4[s];
    ax += wg*sp.x; ay += wg*sp.y; az += wg*sp.z;
  }
  #pragma unroll
  for (int m=32;m>0;m>>=1){
    ax += __shfl_xor(ax, m, 64);
    ay += __shfl_xor(ay, m, 64);
    az += __shfl_xor(az, m, 64);
  }
  if (lane == 0){
    out[(size_t)i*3+0] = ax;
    out[(size_t)i*3+1] = ay;
    out[(size_t)i*3+2] = az;
  }
}

extern "C" void kernel_launch(void* const* d_in, const int* in_sizes, int n_in,
                              void* d_out, int out_size, void* d_ws, size_t ws_size,
                              hipStream_t stream){
  const float* x      = (const float*)d_in[0];
  const int*   ei     = (const int*)  d_in[1];
  const float* eattr  = (const float*)d_in[2];
  const float* in_w   = (const float*)d_in[3];
  const float* in_b   = (const float*)d_in[4];
  const float* ew1    = (const float*)d_in[5];
  const float* eb1    = (const float*)d_in[6];
  const float* ew2    = (const float*)d_in[7];
  const float* eb2    = (const float*)d_in[8];
  const float* nw1    = (const float*)d_in[9];
  const float* nb1    = (const float*)d_in[10];
  const float* nw2    = (const float*)d_in[11];
  const float* nb2    = (const float*)d_in[12];
  const float* ow1    = (const float*)d_in[13];
  const float* ob1    = (const float*)d_in[14];
  const float* ow2    = (const float*)d_in[15];
  const float* ob2    = (const float*)d_in[16];
  float* out = (float*)d_out;

  const int N = in_sizes[0] / 5;
  const int E = in_sizes[1] / 2;

  char* w = (char*)d_ws;
  size_t off = 0;
  auto alloc = [&](size_t bytes)->size_t{
    size_t o = off; off = (off + bytes + 255) & ~(size_t)255; return o;
  };
  size_t o_flag   = alloc(4);
  size_t o_deg    = alloc((size_t)N*4);
  size_t o_offs   = alloc((size_t)N*4);
  size_t o_cursor = alloc((size_t)N*4);
  size_t o_bsum   = alloc(512*4);
  size_t o_spins4 = alloc((size_t)N*16);
  size_t o_ntp    = alloc((size_t)N*8);
  size_t o_wout   = alloc((size_t)N*4);
  size_t o_srcS   = alloc((size_t)E*4);
  size_t o_attrS  = alloc((size_t)E*16);
  size_t o_h      = alloc((size_t)N*128*4);
  size_t o_A      = alloc((size_t)N*128*2);        // bf16
  size_t o_pew2   = alloc((size_t)3*128*128*2);
  size_t o_pnw1   = alloc((size_t)3*256*128*2);
  size_t o_pnw2   = alloc((size_t)3*128*128*2);
  size_t o_pow1   = alloc((size_t)128*128*2);
  if (off > ws_size) return;

  int*    flag   = (int*)   (w + o_flag);
  int*    deg    = (int*)   (w + o_deg);
  int*    offs   = (int*)   (w + o_offs);
  int*    cursor = (int*)   (w + o_cursor);
  int*    bsum   = (int*)   (w + o_bsum);
  float4* spins4 = (float4*)(w + o_spins4);
  float2* ntp    = (float2*)(w + o_ntp);
  float*  wout   = (float*) (w + o_wout);
  int*    srcS   = (int*)   (w + o_srcS);
  float4* attrS  = (float4*)(w + o_attrS);
  float*  h      = (float*) (w + o_h);
  ushort* A      = (ushort*)(w + o_A);
  short*  p_ew2  = (short*) (w + o_pew2);
  short*  p_nw1  = (short*) (w + o_pnw1);
  short*  p_nw2  = (short*) (w + o_pnw2);
  short*  p_ow1  = (short*) (w + o_pow1);

  (void)hipMemsetAsync(deg, 0, (size_t)N*4, stream);

  const int nb = (N + 255) / 256;

  k_detect<<<1, 256, 0, stream>>>(ei, E, flag);
  k_deg<<<(E+255)/256, 256, 0, stream>>>(ei, E, flag, deg);
  k_scan1<<<nb, 256, 0, stream>>>(deg, offs, bsum, N);
  k_scan2<<<1, 512, 0, stream>>>(bsum, nb);
  k_scan3<<<nb, 256, 0, stream>>>(offs, bsum, cursor, N);
  k_node_pre<<<(N+1)/2, 256, 0, stream>>>(x, in_w, in_b, spins4, ntp, h, N);
  k_scatter<<<(E+255)/256, 256, 0, stream>>>(ei, E, flag, eattr, cursor, srcS, attrS);
  k_pack<<<416, 64, 0, stream>>>(ew2, nw1, nw2, ow1, p_ew2, p_nw1, p_nw2, p_ow1);

  const int gb = (N + 63) / 64;
  for (int l=0; l<3; ++l){
    k_edge<<<(N+3)/4, 256, 0, stream>>>(srcS, attrS, spins4, ntp, offs, deg,
                                        ew1 + (size_t)l*10*128, eb1 + (size_t)l*128, A, N);
    k_layer<<<gb, 256, 0, stream>>>(A, h,
                                    p_ew2 + (size_t)l*16384, eb2 + (size_t)l*128,
                                    p_nw1 + (size_t)l*32768, nb1 + (size_t)l*128,
                                    p_nw2 + (size_t)l*16384, nb2 + (size_t)l*128,
                                    deg, N);
  }

  k_out<<<gb, 256, 0, stream>>>(h, p_ow1, ob1, ow2, ob2, wout, N);
  k_bfield<<<(N+3)/4, 256, 0, stream>>>(srcS, spins4, wout, offs, deg, out, N);
}

// Round 5
// 1002.090 us; speedup vs baseline: 1.8724x; 1.1889x over previous
//
#include <hip/hip_runtime.h>
#include <hip/hip_bf16.h>
#include <math.h>

typedef __attribute__((ext_vector_type(8))) short bf16x8;
typedef __attribute__((ext_vector_type(4))) float f32x4;

__device__ __forceinline__ float silu_f(float x){ return x / (1.f + __expf(-x)); }

// fp32 -> bf16 (round-to-nearest-even, finite inputs)
__device__ __forceinline__ short f2bs(float x){
  unsigned u = __builtin_bit_cast(unsigned, x);
  unsigned r = (u + 0x7fffu + ((u >> 16) & 1u)) >> 16;
  return (short)r;
}
__device__ __forceinline__ float bf_lo(unsigned u){ return __builtin_bit_cast(float, u << 16); }
__device__ __forceinline__ float bf_hi(unsigned u){ return __builtin_bit_cast(float, u & 0xffff0000u); }

// ---------------- edge-index layout detect (int64 vs int32) ----------------
__global__ void k_detect(const int* __restrict__ ei, int E, int* __restrict__ flag){
  __shared__ int nz;
  if (threadIdx.x==0) nz = 0;
  __syncthreads();
  int lim = E < 4096 ? E : 4096;
  int c = 0;
  for (int e = threadIdx.x; e < lim; e += blockDim.x)
    if (ei[2*e+1] != 0) c++;
  if (c) atomicAdd(&nz, c);
  __syncthreads();
  if (threadIdx.x==0) *flag = (nz==0) ? 1 : 0;   // 1 => int64 little-endian
}

__global__ __launch_bounds__(256) void k_deg(const int* __restrict__ ei, int E,
                                             const int* __restrict__ flag, int* __restrict__ deg){
  int e = blockIdx.x*blockDim.x + threadIdx.x;
  if (e >= E) return;
  int d = (*flag) ? ei[2*(E+e)] : ei[E+e];
  atomicAdd(&deg[d], 1);
}

// ---------------- exclusive scan over N (2-level) ----------------
__global__ __launch_bounds__(256) void k_scan1(const int* __restrict__ deg, int* __restrict__ offs,
                                               int* __restrict__ bsum, int n){
  __shared__ int sh[256];
  int i = blockIdx.x*256 + threadIdx.x;
  int v = (i < n) ? deg[i] : 0;
  sh[threadIdx.x] = v;
  __syncthreads();
  for (int off=1; off<256; off<<=1){
    int t = (threadIdx.x >= off) ? sh[threadIdx.x-off] : 0;
    __syncthreads();
    sh[threadIdx.x] += t;
    __syncthreads();
  }
  if (i < n) offs[i] = sh[threadIdx.x] - v;
  if (threadIdx.x == 255) bsum[blockIdx.x] = sh[255];
}

__global__ __launch_bounds__(512) void k_scan2(int* __restrict__ bsum, int nb){
  __shared__ int sh[512];
  int v = (threadIdx.x < nb) ? bsum[threadIdx.x] : 0;
  sh[threadIdx.x] = v;
  __syncthreads();
  for (int off=1; off<512; off<<=1){
    int t = (threadIdx.x >= off) ? sh[threadIdx.x-off] : 0;
    __syncthreads();
    sh[threadIdx.x] += t;
    __syncthreads();
  }
  if (threadIdx.x < nb) bsum[threadIdx.x] = sh[threadIdx.x] - v;
}

__global__ __launch_bounds__(256) void k_scan3(int* __restrict__ offs, const int* __restrict__ bsum,
                                               int* __restrict__ cursor, int n){
  int i = blockIdx.x*256 + threadIdx.x;
  if (i >= n) return;
  int o = offs[i] + bsum[i>>8];
  offs[i] = o;
  cursor[i] = o;
}

// ---------------- per-node precompute: normalize spins, h0 ----------------
__global__ __launch_bounds__(256) void k_node_pre(const float* __restrict__ x,
                                                  const float* __restrict__ inw, const float* __restrict__ inb,
                                                  float4* __restrict__ spins4, float2* __restrict__ ntp,
                                                  float* __restrict__ h, int n){
  int half = threadIdx.x >> 7;
  int k = threadIdx.x & 127;
  int i = blockIdx.x*2 + half;
  if (i >= n) return;
  float nt0 = x[i*5+0], nt1 = x[i*5+1];
  float sx = x[i*5+2], sy = x[i*5+3], sz = x[i*5+4];
  float nrm = sqrtf(sx*sx + sy*sy + sz*sz);
  float d = fmaxf(nrm, 1e-12f);
  float mx = sx/d, my = sy/d, mz = sz/d;
  float rn = sqrtf(mx*mx + my*my + mz*mz);
  float v = nt0*inw[k] + nt1*inw[128+k] + rn*inw[256+k] + inb[k];
  h[i*128 + k] = silu_f(v);
  if (k == 0){
    spins4[i] = make_float4(mx, my, mz, rn);
    ntp[i]    = make_float2(nt0, nt1);
  }
}

// ---------------- scatter edges into dst-sorted order + compute 10 edge scalars ----------------
// scE row (16 bf16, 32 B): [|m_i|, |m_j|, mi·mj, mi·u, mj·u, dist, nti0, nti1, ntj0, ntj1, 0...]
__global__ __launch_bounds__(256) void k_scatter(const int* __restrict__ ei, int E,
                                                 const int* __restrict__ flag,
                                                 const float* __restrict__ eattr,
                                                 const float4* __restrict__ spins4,
                                                 const float2* __restrict__ ntp,
                                                 int* __restrict__ cursor,
                                                 int* __restrict__ srcS, ushort* __restrict__ scE){
  int e = blockIdx.x*blockDim.x + threadIdx.x;
  if (e >= E) return;
  int i64 = *flag;
  int s = i64 ? ei[2*e]       : ei[e];
  int d = i64 ? ei[2*(E+e)]   : ei[E+e];
  float4 ea = *(const float4*)(eattr + (size_t)e*4);
  float4 mi = spins4[d];
  float4 mj = spins4[s];
  float2 nti = ntp[d];
  float2 ntj = ntp[s];
  __align__(16) ushort row[16];
  row[0] = (ushort)f2bs(mi.w);
  row[1] = (ushort)f2bs(mj.w);
  row[2] = (ushort)f2bs(mi.x*mj.x + mi.y*mj.y + mi.z*mj.z);
  row[3] = (ushort)f2bs(mi.x*ea.x + mi.y*ea.y + mi.z*ea.z);
  row[4] = (ushort)f2bs(mj.x*ea.x + mj.y*ea.y + mj.z*ea.z);
  row[5] = (ushort)f2bs(ea.w);
  row[6] = (ushort)f2bs(nti.x);
  row[7] = (ushort)f2bs(nti.y);
  row[8] = (ushort)f2bs(ntj.x);
  row[9] = (ushort)f2bs(ntj.y);
  row[10]=0; row[11]=0; row[12]=0; row[13]=0; row[14]=0; row[15]=0;
  int pos = atomicAdd(&cursor[d], 1);
  srcS[pos] = s;
  ushort* dstp = scE + (size_t)pos*16;
  *(uint4*)dstp       = *(uint4*)row;
  *(uint4*)(dstp + 8) = *(uint4*)(row + 8);
}

// ---------------- pack weights to MFMA B-fragment-major bf16 ----------------
// B-frag (16x16x32): lane L holds B[k=(L>>4)*8+e][n=L&15]; tile index = c*8+t
__global__ __launch_bounds__(64) void k_pack(const float* __restrict__ ew2, const float* __restrict__ nw1,
                                             const float* __restrict__ nw2, const float* __restrict__ ow1,
                                             short* __restrict__ p_ew2, short* __restrict__ p_nw1,
                                             short* __restrict__ p_nw2, short* __restrict__ p_ow1){
  int b = blockIdx.x;
  const float* src; short* dst; int tile;
  if (b < 96){        int l = b>>5;              tile = b & 31; src = ew2 + (size_t)l*16384; dst = p_ew2 + (size_t)l*16384; }
  else if (b < 288){  int l = (b-96)>>6;         tile = (b-96) & 63; src = nw1 + (size_t)l*32768; dst = p_nw1 + (size_t)l*32768; }
  else if (b < 384){  int l = (b-288)>>5;        tile = (b-288) & 31; src = nw2 + (size_t)l*16384; dst = p_nw2 + (size_t)l*16384; }
  else {                                          tile = b - 384; src = ow1; dst = p_ow1; }
  int c = tile >> 3, t = tile & 7;
  int L = threadIdx.x;
  int kb  = c*32 + ((L>>4)<<3);
  int col = t*16 + (L&15);
  __align__(16) short tmp[8];
  #pragma unroll
  for (int e=0;e<8;e++) tmp[e] = f2bs(src[(size_t)(kb+e)*128 + col]);
  *(bf16x8*)(dst + ((size_t)tile*64 + L)*8) = *(bf16x8*)tmp;
}

// ---------------- edge MLP hidden sums for ONE layer (wave per node), scE-streaming ----------------
__global__ __launch_bounds__(256) void k_edge(
    const ushort* __restrict__ scE,
    const int* __restrict__ offs, const int* __restrict__ deg,
    const float* __restrict__ ew1l, const float* __restrict__ eb1l,
    ushort* __restrict__ A, int n){
  int wv = threadIdx.x >> 6, lane = threadIdx.x & 63;
  int i = blockIdx.x*4 + wv;
  if (i >= n) return;
  float w[10][2], b0, b1;
  #pragma unroll
  for (int j=0;j<10;j++){
    w[j][0] = ew1l[j*128 + lane];
    w[j][1] = ew1l[j*128 + 64 + lane];
  }
  b0 = eb1l[lane];
  b1 = eb1l[64 + lane];
  int p0 = __builtin_amdgcn_readfirstlane(offs[i]);
  int e  = __builtin_amdgcn_readfirstlane(deg[i]);
  const ushort* rp = scE + (size_t)p0*16;
  float a0 = 0.f, a1 = 0.f;
  for (int q=0;q<e;q++){
    uint4 ra = *(const uint4*)(rp + (size_t)q*16);      // sc0..sc7
    unsigned rb = *(const unsigned*)(rp + (size_t)q*16 + 8); // sc8, sc9
    float s0 = bf_lo(ra.x), s1 = bf_hi(ra.x);
    float s2 = bf_lo(ra.y), s3 = bf_hi(ra.y);
    float s4 = bf_lo(ra.z), s5 = bf_hi(ra.z);
    float s6 = bf_lo(ra.w), s7 = bf_hi(ra.w);
    float s8 = bf_lo(rb),   s9 = bf_hi(rb);
    float t0 = b0, t1 = b1;
    t0 += s0*w[0][0]; t1 += s0*w[0][1];
    t0 += s1*w[1][0]; t1 += s1*w[1][1];
    t0 += s2*w[2][0]; t1 += s2*w[2][1];
    t0 += s3*w[3][0]; t1 += s3*w[3][1];
    t0 += s4*w[4][0]; t1 += s4*w[4][1];
    t0 += s5*w[5][0]; t1 += s5*w[5][1];
    t0 += s6*w[6][0]; t1 += s6*w[6][1];
    t0 += s7*w[7][0]; t1 += s7*w[7][1];
    t0 += s8*w[8][0]; t1 += s8*w[8][1];
    t0 += s9*w[9][0]; t1 += s9*w[9][1];
    a0 += silu_f(t0);
    a1 += silu_f(t1);
  }
  A[(size_t)i*128 + lane]      = (ushort)f2bs(a0);
  A[(size_t)i*128 + 64 + lane] = (ushort)f2bs(a1);
}

// ---------------- MFMA wave GEMM: 16 rows x 128 cols, K = kchunks*32 ----------------
// sIn: bf16 LDS stripe (stride 136); pw: fragment-major packed weights
__device__ __forceinline__ void wave_gemm(const short* __restrict__ sIn, const short* __restrict__ pw,
                                          int lane, int kchunks, f32x4 acc[8]){
  for (int c=0;c<kchunks;c++){
    bf16x8 af = *(const bf16x8*)(sIn + (lane&15)*136 + c*32 + ((lane>>4)<<3));
    const short* pB = pw + (size_t)c*4096 + (size_t)lane*8;
    #pragma unroll
    for (int t=0;t<8;t++){
      bf16x8 bf = *(const bf16x8*)(pB + t*512);
      acc[t] = __builtin_amdgcn_mfma_f32_16x16x32_bf16(af, bf, acc[t], 0, 0, 0);
    }
  }
}

// ---------------- fused per-layer node update (MFMA) ----------------
// aggr = A@ew2 + deg*eb2 ; u = silu([h,aggr]@nw1 + nb1) ; h += u@nw2 + nb2
__global__ __launch_bounds__(256) void k_layer(
    const ushort* __restrict__ A, float* __restrict__ h,
    const short* __restrict__ p_ew2, const float* __restrict__ eb2,
    const short* __restrict__ p_nw1, const float* __restrict__ nb1,
    const short* __restrict__ p_nw2, const float* __restrict__ nb2,
    const int* __restrict__ deg, int n){
  __shared__ __align__(16) short sA[64*136];
  __shared__ __align__(16) short sH[64*136];
  __shared__ __align__(16) short sG[64*136];
  int tid = threadIdx.x;
  int lane = tid & 63, wave = tid >> 6;
  int row0 = blockIdx.x*64;

  // stage A (bf16 copy) and h (fp32 -> bf16)
  #pragma unroll
  for (int q=0;q<8;q++){
    int id = tid + q*256;            // 2048 quads of 4 elems
    int r = id >> 5;
    int cq = (id & 31) << 2;
    int row = row0 + r;
    ushort4 va = make_ushort4(0,0,0,0);
    float4 vh = make_float4(0.f,0.f,0.f,0.f);
    if (row < n){
      va = *(const ushort4*)(A + (size_t)row*128 + cq);
      vh = *(const float4*)(h + (size_t)row*128 + cq);
    }
    *(ushort4*)&sA[r*136 + cq] = va;
    short4 hs; hs.x = f2bs(vh.x); hs.y = f2bs(vh.y); hs.z = f2bs(vh.z); hs.w = f2bs(vh.w);
    *(short4*)&sH[r*136 + cq] = hs;
  }
  __syncthreads();

  const short* sInA = sA + wave*16*136;
  const short* sInH = sH + wave*16*136;
  const short* sInG = sG + wave*16*136;
  int rbase = wave*16 + ((lane>>4)<<2);   // first of this lane's 4 C-rows (block-local)

  f32x4 acc[8];
  const f32x4 zf = {0.f,0.f,0.f,0.f};

  // ---- GEMM-A: aggr = A @ ew2 + deg*eb2 -> sG (bf16) ----
  #pragma unroll
  for (int t=0;t<8;t++) acc[t] = zf;
  wave_gemm(sInA, p_ew2, lane, 4, acc);
  {
    float dd[4];
    #pragma unroll
    for (int r=0;r<4;r++){
      int row = row0 + rbase + r;
      dd[r] = (row < n) ? (float)deg[row] : 0.f;
    }
    #pragma unroll
    for (int t=0;t<8;t++){
      int col = t*16 + (lane&15);
      float bv = eb2[col];
      #pragma unroll
      for (int r=0;r<4;r++)
        sG[(rbase+r)*136 + col] = f2bs(acc[t][r] + dd[r]*bv);
    }
  }
  __syncthreads();

  // ---- GEMM-B: u = silu([h|aggr] @ nw1 + nb1) -> sA (bf16) ----
  #pragma unroll
  for (int t=0;t<8;t++) acc[t] = zf;
  wave_gemm(sInH, p_nw1,         lane, 4, acc);
  wave_gemm(sInG, p_nw1 + 16384, lane, 4, acc);
  __syncthreads();   // everyone done reading sA (GEMM-A) before overwrite
  {
    #pragma unroll
    for (int t=0;t<8;t++){
      int col = t*16 + (lane&15);
      float bv = nb1[col];
      #pragma unroll
      for (int r=0;r<4;r++)
        sA[(rbase+r)*136 + col] = f2bs(silu_f(acc[t][r] + bv));
    }
  }
  __syncthreads();

  // ---- GEMM-C: h += u @ nw2 + nb2 ----
  #pragma unroll
  for (int t=0;t<8;t++) acc[t] = zf;
  wave_gemm(sInA, p_nw2, lane, 4, acc);
  {
    #pragma unroll
    for (int t=0;t<8;t++){
      int col = t*16 + (lane&15);
      float bv = nb2[col];
      #pragma unroll
      for (int r=0;r<4;r++){
        int row = row0 + rbase + r;
        if (row < n){
          size_t idx = (size_t)row*128 + col;
          h[idx] = h[idx] + acc[t][r] + bv;
        }
      }
    }
  }
}

// ---------------- fused output head (MFMA): wout = silu(h@ow1+ob1)·ow2 + ob2 ----------------
__global__ __launch_bounds__(256) void k_out(const float* __restrict__ h,
                                             const short* __restrict__ p_ow1, const float* __restrict__ ob1,
                                             const float* __restrict__ ow2, const float* __restrict__ ob2,
                                             float* __restrict__ wout, int n){
  __shared__ __align__(16) short sH[64*136];
  int tid = threadIdx.x;
  int lane = tid & 63, wave = tid >> 6;
  int row0 = blockIdx.x*64;
  #pragma unroll
  for (int q=0;q<8;q++){
    int id = tid + q*256;
    int r = id >> 5;
    int cq = (id & 31) << 2;
    int row = row0 + r;
    float4 vh = make_float4(0.f,0.f,0.f,0.f);
    if (row < n) vh = *(const float4*)(h + (size_t)row*128 + cq);
    short4 hs; hs.x = f2bs(vh.x); hs.y = f2bs(vh.y); hs.z = f2bs(vh.z); hs.w = f2bs(vh.w);
    *(short4*)&sH[r*136 + cq] = hs;
  }
  __syncthreads();

  f32x4 acc[8];
  const f32x4 zf = {0.f,0.f,0.f,0.f};
  #pragma unroll
  for (int t=0;t<8;t++) acc[t] = zf;
  wave_gemm(sH + wave*16*136, p_ow1, lane, 4, acc);

  float p[4] = {0.f,0.f,0.f,0.f};
  #pragma unroll
  for (int t=0;t<8;t++){
    int col = t*16 + (lane&15);
    float b1 = ob1[col], w2 = ow2[col];
    #pragma unroll
    for (int r=0;r<4;r++) p[r] += silu_f(acc[t][r] + b1)*w2;
  }
  #pragma unroll
  for (int m=1;m<16;m<<=1){
    #pragma unroll
    for (int r=0;r<4;r++) p[r] += __shfl_xor(p[r], m, 64);
  }
  if ((lane & 15) == 0){
    float b = ob2[0];
    #pragma unroll
    for (int r=0;r<4;r++){
      int row = row0 + wave*16 + ((lane>>4)<<2) + r;
      if (row < n) wout[row] = p[r] + b;
    }
  }
}

// ---------------- b_field: gather-sum weight[src]*spins[src] per node ----------------
__global__ __launch_bounds__(256) void k_bfield(const int* __restrict__ srcS, const float4* __restrict__ spins4,
                                                const float* __restrict__ wout, const int* __restrict__ offs,
                                                const int* __restrict__ deg, float* __restrict__ out, int n){
  int wv = threadIdx.x >> 6, lane = threadIdx.x & 63;
  int i = blockIdx.x*4 + wv;
  if (i >= n) return;
  int p0 = offs[i], e = deg[i];
  float ax=0.f, ay=0.f, az=0.f;
  for (int q=lane; q<e; q+=64){
    int s = srcS[p0+q];
    float wg = wout[s];
    float4 sp = spins4[s];
    ax += wg*sp.x; ay += wg*sp.y; az += wg*sp.z;
  }
  #pragma unroll
  for (int m=32;m>0;m>>=1){
    ax += __shfl_xor(ax, m, 64);
    ay += __shfl_xor(ay, m, 64);
    az += __shfl_xor(az, m, 64);
  }
  if (lane == 0){
    out[(size_t)i*3+0] = ax;
    out[(size_t)i*3+1] = ay;
    out[(size_t)i*3+2] = az;
  }
}

extern "C" void kernel_launch(void* const* d_in, const int* in_sizes, int n_in,
                              void* d_out, int out_size, void* d_ws, size_t ws_size,
                              hipStream_t stream){
  const float* x      = (const float*)d_in[0];
  const int*   ei     = (const int*)  d_in[1];
  const float* eattr  = (const float*)d_in[2];
  const float* in_w   = (const float*)d_in[3];
  const float* in_b   = (const float*)d_in[4];
  const float* ew1    = (const float*)d_in[5];
  const float* eb1    = (const float*)d_in[6];
  const float* ew2    = (const float*)d_in[7];
  const float* eb2    = (const float*)d_in[8];
  const float* nw1    = (const float*)d_in[9];
  const float* nb1    = (const float*)d_in[10];
  const float* nw2    = (const float*)d_in[11];
  const float* nb2    = (const float*)d_in[12];
  const float* ow1    = (const float*)d_in[13];
  const float* ob1    = (const float*)d_in[14];
  const float* ow2    = (const float*)d_in[15];
  const float* ob2    = (const float*)d_in[16];
  float* out = (float*)d_out;

  const int N = in_sizes[0] / 5;
  const int E = in_sizes[1] / 2;

  char* w = (char*)d_ws;
  size_t off = 0;
  auto alloc = [&](size_t bytes)->size_t{
    size_t o = off; off = (off + bytes + 255) & ~(size_t)255; return o;
  };
  size_t o_flag   = alloc(4);
  size_t o_deg    = alloc((size_t)N*4);
  size_t o_offs   = alloc((size_t)N*4);
  size_t o_cursor = alloc((size_t)N*4);
  size_t o_bsum   = alloc(512*4);
  size_t o_spins4 = alloc((size_t)N*16);
  size_t o_ntp    = alloc((size_t)N*8);
  size_t o_wout   = alloc((size_t)N*4);
  size_t o_srcS   = alloc((size_t)E*4);
  size_t o_scE    = alloc((size_t)E*16*2);         // bf16 16-col rows
  size_t o_h      = alloc((size_t)N*128*4);
  size_t o_A      = alloc((size_t)N*128*2);        // bf16
  size_t o_pew2   = alloc((size_t)3*128*128*2);
  size_t o_pnw1   = alloc((size_t)3*256*128*2);
  size_t o_pnw2   = alloc((size_t)3*128*128*2);
  size_t o_pow1   = alloc((size_t)128*128*2);
  if (off > ws_size) return;

  int*    flag   = (int*)   (w + o_flag);
  int*    deg    = (int*)   (w + o_deg);
  int*    offs   = (int*)   (w + o_offs);
  int*    cursor = (int*)   (w + o_cursor);
  int*    bsum   = (int*)   (w + o_bsum);
  float4* spins4 = (float4*)(w + o_spins4);
  float2* ntp    = (float2*)(w + o_ntp);
  float*  wout   = (float*) (w + o_wout);
  int*    srcS   = (int*)   (w + o_srcS);
  ushort* scE    = (ushort*)(w + o_scE);
  float*  h      = (float*) (w + o_h);
  ushort* A      = (ushort*)(w + o_A);
  short*  p_ew2  = (short*) (w + o_pew2);
  short*  p_nw1  = (short*) (w + o_pnw1);
  short*  p_nw2  = (short*) (w + o_pnw2);
  short*  p_ow1  = (short*) (w + o_pow1);

  (void)hipMemsetAsync(deg, 0, (size_t)N*4, stream);

  const int nb = (N + 255) / 256;

  k_detect<<<1, 256, 0, stream>>>(ei, E, flag);
  k_deg<<<(E+255)/256, 256, 0, stream>>>(ei, E, flag, deg);
  k_scan1<<<nb, 256, 0, stream>>>(deg, offs, bsum, N);
  k_scan2<<<1, 512, 0, stream>>>(bsum, nb);
  k_scan3<<<nb, 256, 0, stream>>>(offs, bsum, cursor, N);
  k_node_pre<<<(N+1)/2, 256, 0, stream>>>(x, in_w, in_b, spins4, ntp, h, N);
  k_scatter<<<(E+255)/256, 256, 0, stream>>>(ei, E, flag, eattr, spins4, ntp, cursor, srcS, scE);
  k_pack<<<416, 64, 0, stream>>>(ew2, nw1, nw2, ow1, p_ew2, p_nw1, p_nw2, p_ow1);

  const int gb = (N + 63) / 64;
  for (int l=0; l<3; ++l){
    k_edge<<<(N+3)/4, 256, 0, stream>>>(scE, offs, deg,
                                        ew1 + (size_t)l*10*128, eb1 + (size_t)l*128, A, N);
    k_layer<<<gb, 256, 0, stream>>>(A, h,
                                    p_ew2 + (size_t)l*16384, eb2 + (size_t)l*128,
                                    p_nw1 + (size_t)l*32768, nb1 + (size_t)l*128,
                                    p_nw2 + (size_t)l*16384, nb2 + (size_t)l*128,
                                    deg, N);
  }

  k_out<<<gb, 256, 0, stream>>>(h, p_ow1, ob1, ow2, ob2, wout, N);
  k_bfield<<<(N+3)/4, 256, 0, stream>>>(srcS, spins4, wout, offs, deg, out, N);
}

// Round 6
// 883.175 us; speedup vs baseline: 2.1245x; 1.1346x over previous
//
#include <hip/hip_runtime.h>
#include <hip/hip_bf16.h>
#include <math.h>

typedef __attribute__((ext_vector_type(8))) short bf16x8;
typedef __attribute__((ext_vector_type(4))) float f32x4;

// silu via fast rcp (avoids IEEE div expansion); ~1ulp rcp, negligible vs bf16 noise
__device__ __forceinline__ float silu_f(float x){
  return x * __builtin_amdgcn_rcpf(1.f + __expf(-x));
}

// fp32 -> bf16 (round-to-nearest-even, finite inputs)
__device__ __forceinline__ short f2bs(float x){
  unsigned u = __builtin_bit_cast(unsigned, x);
  unsigned r = (u + 0x7fffu + ((u >> 16) & 1u)) >> 16;
  return (short)r;
}

// ---------------- edge-index layout detect (int64 vs int32) ----------------
__global__ void k_detect(const int* __restrict__ ei, int E, int* __restrict__ flag){
  __shared__ int nz;
  if (threadIdx.x==0) nz = 0;
  __syncthreads();
  int lim = E < 4096 ? E : 4096;
  int c = 0;
  for (int e = threadIdx.x; e < lim; e += blockDim.x)
    if (ei[2*e+1] != 0) c++;
  if (c) atomicAdd(&nz, c);
  __syncthreads();
  if (threadIdx.x==0) *flag = (nz==0) ? 1 : 0;   // 1 => int64 little-endian
}

__global__ __launch_bounds__(256) void k_deg(const int* __restrict__ ei, int E,
                                             const int* __restrict__ flag, int* __restrict__ deg){
  int e = blockIdx.x*blockDim.x + threadIdx.x;
  if (e >= E) return;
  int d = (*flag) ? ei[2*(E+e)] : ei[E+e];
  atomicAdd(&deg[d], 1);
}

// ---------------- exclusive scan over N (2-level) ----------------
__global__ __launch_bounds__(256) void k_scan1(const int* __restrict__ deg, int* __restrict__ offs,
                                               int* __restrict__ bsum, int n){
  __shared__ int sh[256];
  int i = blockIdx.x*256 + threadIdx.x;
  int v = (i < n) ? deg[i] : 0;
  sh[threadIdx.x] = v;
  __syncthreads();
  for (int off=1; off<256; off<<=1){
    int t = (threadIdx.x >= off) ? sh[threadIdx.x-off] : 0;
    __syncthreads();
    sh[threadIdx.x] += t;
    __syncthreads();
  }
  if (i < n) offs[i] = sh[threadIdx.x] - v;
  if (threadIdx.x == 255) bsum[blockIdx.x] = sh[255];
}

__global__ __launch_bounds__(512) void k_scan2(int* __restrict__ bsum, int nb){
  __shared__ int sh[512];
  int v = (threadIdx.x < nb) ? bsum[threadIdx.x] : 0;
  sh[threadIdx.x] = v;
  __syncthreads();
  for (int off=1; off<512; off<<=1){
    int t = (threadIdx.x >= off) ? sh[threadIdx.x-off] : 0;
    __syncthreads();
    sh[threadIdx.x] += t;
    __syncthreads();
  }
  if (threadIdx.x < nb) bsum[threadIdx.x] = sh[threadIdx.x] - v;
}

__global__ __launch_bounds__(256) void k_scan3(int* __restrict__ offs, const int* __restrict__ bsum,
                                               int* __restrict__ cursor, int n){
  int i = blockIdx.x*256 + threadIdx.x;
  if (i >= n) return;
  int o = offs[i] + bsum[i>>8];
  offs[i] = o;
  cursor[i] = o;
}

// ---------------- per-node precompute: normalize spins, h0 ----------------
__global__ __launch_bounds__(256) void k_node_pre(const float* __restrict__ x,
                                                  const float* __restrict__ inw, const float* __restrict__ inb,
                                                  float4* __restrict__ spins4, float2* __restrict__ ntp,
                                                  float* __restrict__ h, int n){
  int half = threadIdx.x >> 7;
  int k = threadIdx.x & 127;
  int i = blockIdx.x*2 + half;
  if (i >= n) return;
  float nt0 = x[i*5+0], nt1 = x[i*5+1];
  float sx = x[i*5+2], sy = x[i*5+3], sz = x[i*5+4];
  float nrm = sqrtf(sx*sx + sy*sy + sz*sz);
  float d = fmaxf(nrm, 1e-12f);
  float mx = sx/d, my = sy/d, mz = sz/d;
  float rn = sqrtf(mx*mx + my*my + mz*mz);
  float v = nt0*inw[k] + nt1*inw[128+k] + rn*inw[256+k] + inb[k];
  h[i*128 + k] = silu_f(v);
  if (k == 0){
    spins4[i] = make_float4(mx, my, mz, rn);
    ntp[i]    = make_float2(nt0, nt1);
  }
}

// ---------------- scatter edges into dst-sorted order + compute edge scalars ----------------
// scE row (16 bf16, 32 B): [|m_i|,|m_j|,mi·mj,mi·u,mj·u,dist,nti0,nti1,ntj0,ntj1, 1.0, 0...]
// index 10 = constant 1.0 so the edge-MLP bias rides as B's k=10 row (zero-padded edges -> silu(0)=0)
__global__ __launch_bounds__(256) void k_scatter(const int* __restrict__ ei, int E,
                                                 const int* __restrict__ flag,
                                                 const float* __restrict__ eattr,
                                                 const float4* __restrict__ spins4,
                                                 const float2* __restrict__ ntp,
                                                 int* __restrict__ cursor,
                                                 int* __restrict__ srcS, ushort* __restrict__ scE){
  int e = blockIdx.x*blockDim.x + threadIdx.x;
  if (e >= E) return;
  int i64 = *flag;
  int s = i64 ? ei[2*e]       : ei[e];
  int d = i64 ? ei[2*(E+e)]   : ei[E+e];
  float4 ea = *(const float4*)(eattr + (size_t)e*4);
  float4 mi = spins4[d];
  float4 mj = spins4[s];
  float2 nti = ntp[d];
  float2 ntj = ntp[s];
  __align__(16) ushort row[16];
  row[0] = (ushort)f2bs(mi.w);
  row[1] = (ushort)f2bs(mj.w);
  row[2] = (ushort)f2bs(mi.x*mj.x + mi.y*mj.y + mi.z*mj.z);
  row[3] = (ushort)f2bs(mi.x*ea.x + mi.y*ea.y + mi.z*ea.z);
  row[4] = (ushort)f2bs(mj.x*ea.x + mj.y*ea.y + mj.z*ea.z);
  row[5] = (ushort)f2bs(ea.w);
  row[6] = (ushort)f2bs(nti.x);
  row[7] = (ushort)f2bs(nti.y);
  row[8] = (ushort)f2bs(ntj.x);
  row[9] = (ushort)f2bs(ntj.y);
  row[10]= 0x3F80;  // 1.0 bf16
  row[11]=0; row[12]=0; row[13]=0; row[14]=0; row[15]=0;
  int pos = atomicAdd(&cursor[d], 1);
  srcS[pos] = s;
  ushort* dstp = scE + (size_t)pos*16;
  *(uint4*)dstp       = *(uint4*)row;
  *(uint4*)(dstp + 8) = *(uint4*)(row + 8);
}

// ---------------- pack weights to MFMA B-fragment-major bf16 ----------------
// B-frag (16x16x32): lane L holds B[k=(L>>4)*8+e][n=L&15]; tile index = c*8+t
// blocks 416..439: ew1 (10x128, +bias row k=10, zero-pad to K=32, c=0 only)
__global__ __launch_bounds__(64) void k_pack(const float* __restrict__ ew2, const float* __restrict__ nw1,
                                             const float* __restrict__ nw2, const float* __restrict__ ow1,
                                             const float* __restrict__ ew1, const float* __restrict__ eb1,
                                             short* __restrict__ p_ew2, short* __restrict__ p_nw1,
                                             short* __restrict__ p_nw2, short* __restrict__ p_ow1,
                                             short* __restrict__ p_ew1){
  int b = blockIdx.x;
  int L = threadIdx.x;
  if (b >= 416){
    int tile = b - 416;          // 0..23
    int l = tile >> 3, t = tile & 7;
    int col = t*16 + (L & 15);
    int kb  = (L >> 4) << 3;
    __align__(16) short tmp[8];
    #pragma unroll
    for (int e=0;e<8;e++){
      int k = kb + e;
      float v = 0.f;
      if (k < 10)      v = ew1[(size_t)l*1280 + (size_t)k*128 + col];
      else if (k == 10) v = eb1[(size_t)l*128 + col];
      tmp[e] = f2bs(v);
    }
    *(bf16x8*)(p_ew1 + (size_t)l*4096 + t*512 + L*8) = *(bf16x8*)tmp;
    return;
  }
  const float* src; short* dst; int tile;
  if (b < 96){        int l = b>>5;              tile = b & 31; src = ew2 + (size_t)l*16384; dst = p_ew2 + (size_t)l*16384; }
  else if (b < 288){  int l = (b-96)>>6;         tile = (b-96) & 63; src = nw1 + (size_t)l*32768; dst = p_nw1 + (size_t)l*32768; }
  else if (b < 384){  int l = (b-288)>>5;        tile = (b-288) & 31; src = nw2 + (size_t)l*16384; dst = p_nw2 + (size_t)l*16384; }
  else {                                          tile = b - 384; src = ow1; dst = p_ow1; }
  int c = tile >> 3, t = tile & 7;
  int kb  = c*32 + ((L>>4)<<3);
  int col = t*16 + (L&15);
  __align__(16) short tmp[8];
  #pragma unroll
  for (int e=0;e<8;e++) tmp[e] = f2bs(src[(size_t)(kb+e)*128 + col]);
  *(bf16x8*)(dst + ((size_t)tile*64 + L)*8) = *(bf16x8*)tmp;
}

// ---------------- edge MLP hidden sums for ONE layer (wave per node), MFMA ----------------
// A = 16 edges x K32 (scE rows ARE the A-fragment; quads 2-3 zero);
// B = packed ew1 (bias in k=10); invalid edges -> zero A-row -> silu(0)=0 -> no masking.
__global__ __launch_bounds__(256) void k_edge(
    const ushort* __restrict__ scE,
    const int* __restrict__ offs, const int* __restrict__ deg,
    const short* __restrict__ p_ew1l,
    ushort* __restrict__ A, int n){
  int wv = threadIdx.x >> 6, lane = threadIdx.x & 63;
  int i = blockIdx.x*4 + wv;
  if (i >= n) return;
  int quad = lane >> 4, lr = lane & 15;
  bf16x8 Bf[8];
  #pragma unroll
  for (int t=0;t<8;t++) Bf[t] = *(const bf16x8*)(p_ew1l + t*512 + lane*8);
  int p0 = __builtin_amdgcn_readfirstlane(offs[i]);
  int dg = __builtin_amdgcn_readfirstlane(deg[i]);
  float s[8];
  #pragma unroll
  for (int t=0;t<8;t++) s[t] = 0.f;
  const f32x4 zf = {0.f,0.f,0.f,0.f};
  const uint4 z4 = {0u,0u,0u,0u};
  for (int g=0; g<dg; g+=16){
    int e = g + lr;
    uint4 d4 = z4;
    if (quad < 2 && e < dg)
      d4 = *(const uint4*)(scE + ((size_t)(p0+e))*16 + quad*8);
    bf16x8 af = __builtin_bit_cast(bf16x8, d4);
    f32x4 acc[8];
    #pragma unroll
    for (int t=0;t<8;t++)
      acc[t] = __builtin_amdgcn_mfma_f32_16x16x32_bf16(af, Bf[t], zf, 0, 0, 0);
    #pragma unroll
    for (int t=0;t<8;t++)
      s[t] += silu_f(acc[t][0]) + silu_f(acc[t][1]) + silu_f(acc[t][2]) + silu_f(acc[t][3]);
  }
  #pragma unroll
  for (int t=0;t<8;t++){
    s[t] += __shfl_xor(s[t], 16, 64);
    s[t] += __shfl_xor(s[t], 32, 64);
  }
  if (quad == 0){
    #pragma unroll
    for (int t=0;t<8;t++)
      A[(size_t)i*128 + t*16 + lr] = (ushort)f2bs(s[t]);
  }
}

// ---------------- MFMA wave GEMM: 16 rows x 128 cols, K = kchunks*32 ----------------
__device__ __forceinline__ void wave_gemm(const short* __restrict__ sIn, const short* __restrict__ pw,
                                          int lane, int kchunks, f32x4 acc[8]){
  for (int c=0;c<kchunks;c++){
    bf16x8 af = *(const bf16x8*)(sIn + (lane&15)*136 + c*32 + ((lane>>4)<<3));
    const short* pB = pw + (size_t)c*4096 + (size_t)lane*8;
    #pragma unroll
    for (int t=0;t<8;t++){
      bf16x8 bf = *(const bf16x8*)(pB + t*512);
      acc[t] = __builtin_amdgcn_mfma_f32_16x16x32_bf16(af, bf, acc[t], 0, 0, 0);
    }
  }
}

// ---------------- fused per-layer node update (MFMA) ----------------
// aggr = A@ew2 + deg*eb2 ; u = silu([h,aggr]@nw1 + nb1) ; h += u@nw2 + nb2
__global__ __launch_bounds__(256) void k_layer(
    const ushort* __restrict__ A, float* __restrict__ h,
    const short* __restrict__ p_ew2, const float* __restrict__ eb2,
    const short* __restrict__ p_nw1, const float* __restrict__ nb1,
    const short* __restrict__ p_nw2, const float* __restrict__ nb2,
    const int* __restrict__ deg, int n){
  __shared__ __align__(16) short sA[64*136];
  __shared__ __align__(16) short sH[64*136];
  __shared__ __align__(16) short sG[64*136];
  int tid = threadIdx.x;
  int lane = tid & 63, wave = tid >> 6;
  int row0 = blockIdx.x*64;

  #pragma unroll
  for (int q=0;q<8;q++){
    int id = tid + q*256;
    int r = id >> 5;
    int cq = (id & 31) << 2;
    int row = row0 + r;
    ushort4 va = make_ushort4(0,0,0,0);
    float4 vh = make_float4(0.f,0.f,0.f,0.f);
    if (row < n){
      va = *(const ushort4*)(A + (size_t)row*128 + cq);
      vh = *(const float4*)(h + (size_t)row*128 + cq);
    }
    *(ushort4*)&sA[r*136 + cq] = va;
    short4 hs; hs.x = f2bs(vh.x); hs.y = f2bs(vh.y); hs.z = f2bs(vh.z); hs.w = f2bs(vh.w);
    *(short4*)&sH[r*136 + cq] = hs;
  }
  __syncthreads();

  const short* sInA = sA + wave*16*136;
  const short* sInH = sH + wave*16*136;
  const short* sInG = sG + wave*16*136;
  int rbase = wave*16 + ((lane>>4)<<2);

  f32x4 acc[8];
  const f32x4 zf = {0.f,0.f,0.f,0.f};

  // ---- GEMM-A: aggr = A @ ew2 + deg*eb2 -> sG (bf16) ----
  #pragma unroll
  for (int t=0;t<8;t++) acc[t] = zf;
  wave_gemm(sInA, p_ew2, lane, 4, acc);
  {
    float dd[4];
    #pragma unroll
    for (int r=0;r<4;r++){
      int row = row0 + rbase + r;
      dd[r] = (row < n) ? (float)deg[row] : 0.f;
    }
    #pragma unroll
    for (int t=0;t<8;t++){
      int col = t*16 + (lane&15);
      float bv = eb2[col];
      #pragma unroll
      for (int r=0;r<4;r++)
        sG[(rbase+r)*136 + col] = f2bs(acc[t][r] + dd[r]*bv);
    }
  }
  __syncthreads();

  // ---- GEMM-B: u = silu([h|aggr] @ nw1 + nb1) -> sA (bf16) ----
  #pragma unroll
  for (int t=0;t<8;t++) acc[t] = zf;
  wave_gemm(sInH, p_nw1,         lane, 4, acc);
  wave_gemm(sInG, p_nw1 + 16384, lane, 4, acc);
  __syncthreads();
  {
    #pragma unroll
    for (int t=0;t<8;t++){
      int col = t*16 + (lane&15);
      float bv = nb1[col];
      #pragma unroll
      for (int r=0;r<4;r++)
        sA[(rbase+r)*136 + col] = f2bs(silu_f(acc[t][r] + bv));
    }
  }
  __syncthreads();

  // ---- GEMM-C: h += u @ nw2 + nb2 ----
  #pragma unroll
  for (int t=0;t<8;t++) acc[t] = zf;
  wave_gemm(sInA, p_nw2, lane, 4, acc);
  {
    #pragma unroll
    for (int t=0;t<8;t++){
      int col = t*16 + (lane&15);
      float bv = nb2[col];
      #pragma unroll
      for (int r=0;r<4;r++){
        int row = row0 + rbase + r;
        if (row < n){
          size_t idx = (size_t)row*128 + col;
          h[idx] = h[idx] + acc[t][r] + bv;
        }
      }
    }
  }
}

// ---------------- fused output head (MFMA): wout = silu(h@ow1+ob1)·ow2 + ob2 ----------------
__global__ __launch_bounds__(256) void k_out(const float* __restrict__ h,
                                             const short* __restrict__ p_ow1, const float* __restrict__ ob1,
                                             const float* __restrict__ ow2, const float* __restrict__ ob2,
                                             float* __restrict__ wout, int n){
  __shared__ __align__(16) short sH[64*136];
  int tid = threadIdx.x;
  int lane = tid & 63, wave = tid >> 6;
  int row0 = blockIdx.x*64;
  #pragma unroll
  for (int q=0;q<8;q++){
    int id = tid + q*256;
    int r = id >> 5;
    int cq = (id & 31) << 2;
    int row = row0 + r;
    float4 vh = make_float4(0.f,0.f,0.f,0.f);
    if (row < n) vh = *(const float4*)(h + (size_t)row*128 + cq);
    short4 hs; hs.x = f2bs(vh.x); hs.y = f2bs(vh.y); hs.z = f2bs(vh.z); hs.w = f2bs(vh.w);
    *(short4*)&sH[r*136 + cq] = hs;
  }
  __syncthreads();

  f32x4 acc[8];
  const f32x4 zf = {0.f,0.f,0.f,0.f};
  #pragma unroll
  for (int t=0;t<8;t++) acc[t] = zf;
  wave_gemm(sH + wave*16*136, p_ow1, lane, 4, acc);

  float p[4] = {0.f,0.f,0.f,0.f};
  #pragma unroll
  for (int t=0;t<8;t++){
    int col = t*16 + (lane&15);
    float b1 = ob1[col], w2 = ow2[col];
    #pragma unroll
    for (int r=0;r<4;r++) p[r] += silu_f(acc[t][r] + b1)*w2;
  }
  #pragma unroll
  for (int m=1;m<16;m<<=1){
    #pragma unroll
    for (int r=0;r<4;r++) p[r] += __shfl_xor(p[r], m, 64);
  }
  if ((lane & 15) == 0){
    float b = ob2[0];
    #pragma unroll
    for (int r=0;r<4;r++){
      int row = row0 + wave*16 + ((lane>>4)<<2) + r;
      if (row < n) wout[row] = p[r] + b;
    }
  }
}

// ---------------- b_field: gather-sum weight[src]*spins[src] per node ----------------
__global__ __launch_bounds__(256) void k_bfield(const int* __restrict__ srcS, const float4* __restrict__ spins4,
                                                const float* __restrict__ wout, const int* __restrict__ offs,
                                                const int* __restrict__ deg, float* __restrict__ out, int n){
  int wv = threadIdx.x >> 6, lane = threadIdx.x & 63;
  int i = blockIdx.x*4 + wv;
  if (i >= n) return;
  int p0 = offs[i], e = deg[i];
  float ax=0.f, ay=0.f, az=0.f;
  for (int q=lane; q<e; q+=64){
    int s = srcS[p0+q];
    float wg = wout[s];
    float4 sp = spins4[s];
    ax += wg*sp.x; ay += wg*sp.y; az += wg*sp.z;
  }
  #pragma unroll
  for (int m=32;m>0;m>>=1){
    ax += __shfl_xor(ax, m, 64);
    ay += __shfl_xor(ay, m, 64);
    az += __shfl_xor(az, m, 64);
  }
  if (lane == 0){
    out[(size_t)i*3+0] = ax;
    out[(size_t)i*3+1] = ay;
    out[(size_t)i*3+2] = az;
  }
}

extern "C" void kernel_launch(void* const* d_in, const int* in_sizes, int n_in,
                              void* d_out, int out_size, void* d_ws, size_t ws_size,
                              hipStream_t stream){
  const float* x      = (const float*)d_in[0];
  const int*   ei     = (const int*)  d_in[1];
  const float* eattr  = (const float*)d_in[2];
  const float* in_w   = (const float*)d_in[3];
  const float* in_b   = (const float*)d_in[4];
  const float* ew1    = (const float*)d_in[5];
  const float* eb1    = (const float*)d_in[6];
  const float* ew2    = (const float*)d_in[7];
  const float* eb2    = (const float*)d_in[8];
  const float* nw1    = (const float*)d_in[9];
  const float* nb1    = (const float*)d_in[10];
  const float* nw2    = (const float*)d_in[11];
  const float* nb2    = (const float*)d_in[12];
  const float* ow1    = (const float*)d_in[13];
  const float* ob1    = (const float*)d_in[14];
  const float* ow2    = (const float*)d_in[15];
  const float* ob2    = (const float*)d_in[16];
  float* out = (float*)d_out;

  const int N = in_sizes[0] / 5;
  const int E = in_sizes[1] / 2;

  char* w = (char*)d_ws;
  size_t off = 0;
  auto alloc = [&](size_t bytes)->size_t{
    size_t o = off; off = (off + bytes + 255) & ~(size_t)255; return o;
  };
  size_t o_flag   = alloc(4);
  size_t o_deg    = alloc((size_t)N*4);
  size_t o_offs   = alloc((size_t)N*4);
  size_t o_cursor = alloc((size_t)N*4);
  size_t o_bsum   = alloc(512*4);
  size_t o_spins4 = alloc((size_t)N*16);
  size_t o_ntp    = alloc((size_t)N*8);
  size_t o_wout   = alloc((size_t)N*4);
  size_t o_srcS   = alloc((size_t)E*4);
  size_t o_scE    = alloc((size_t)E*16*2);
  size_t o_h      = alloc((size_t)N*128*4);
  size_t o_A      = alloc((size_t)N*128*2);
  size_t o_pew2   = alloc((size_t)3*128*128*2);
  size_t o_pnw1   = alloc((size_t)3*256*128*2);
  size_t o_pnw2   = alloc((size_t)3*128*128*2);
  size_t o_pow1   = alloc((size_t)128*128*2);
  size_t o_pew1   = alloc((size_t)3*4096*2);
  if (off > ws_size) return;

  int*    flag   = (int*)   (w + o_flag);
  int*    deg    = (int*)   (w + o_deg);
  int*    offs   = (int*)   (w + o_offs);
  int*    cursor = (int*)   (w + o_cursor);
  int*    bsum   = (int*)   (w + o_bsum);
  float4* spins4 = (float4*)(w + o_spins4);
  float2* ntp    = (float2*)(w + o_ntp);
  float*  wout   = (float*) (w + o_wout);
  int*    srcS   = (int*)   (w + o_srcS);
  ushort* scE    = (ushort*)(w + o_scE);
  float*  h      = (float*) (w + o_h);
  ushort* A      = (ushort*)(w + o_A);
  short*  p_ew2  = (short*) (w + o_pew2);
  short*  p_nw1  = (short*) (w + o_pnw1);
  short*  p_nw2  = (short*) (w + o_pnw2);
  short*  p_ow1  = (short*) (w + o_pow1);
  short*  p_ew1  = (short*) (w + o_pew1);

  (void)hipMemsetAsync(deg, 0, (size_t)N*4, stream);

  const int nb = (N + 255) / 256;

  k_detect<<<1, 256, 0, stream>>>(ei, E, flag);
  k_deg<<<(E+255)/256, 256, 0, stream>>>(ei, E, flag, deg);
  k_scan1<<<nb, 256, 0, stream>>>(deg, offs, bsum, N);
  k_scan2<<<1, 512, 0, stream>>>(bsum, nb);
  k_scan3<<<nb, 256, 0, stream>>>(offs, bsum, cursor, N);
  k_node_pre<<<(N+1)/2, 256, 0, stream>>>(x, in_w, in_b, spins4, ntp, h, N);
  k_scatter<<<(E+255)/256, 256, 0, stream>>>(ei, E, flag, eattr, spins4, ntp, cursor, srcS, scE);
  k_pack<<<440, 64, 0, stream>>>(ew2, nw1, nw2, ow1, ew1, eb1,
                                 p_ew2, p_nw1, p_nw2, p_ow1, p_ew1);

  const int gb = (N + 63) / 64;
  for (int l=0; l<3; ++l){
    k_edge<<<(N+3)/4, 256, 0, stream>>>(scE, offs, deg, p_ew1 + (size_t)l*4096, A, N);
    k_layer<<<gb, 256, 0, stream>>>(A, h,
                                    p_ew2 + (size_t)l*16384, eb2 + (size_t)l*128,
                                    p_nw1 + (size_t)l*32768, nb1 + (size_t)l*128,
                                    p_nw2 + (size_t)l*16384, nb2 + (size_t)l*128,
                                    deg, N);
  }

  k_out<<<gb, 256, 0, stream>>>(h, p_ow1, ob1, ow2, ob2, wout, N);
  k_bfield<<<(N+3)/4, 256, 0, stream>>>(srcS, spins4, wout, offs, deg, out, N);
}